// Round 11
// baseline (398.645 us; speedup 1.0000x reference)
//
#include <hip/hip_runtime.h>
#include <hip/hip_bf16.h>

#define HD 128

typedef unsigned int u32;
typedef unsigned short u16;
typedef __attribute__((ext_vector_type(8))) short short8;   // 8 bf16 (4 VGPRs)
typedef __attribute__((ext_vector_type(4))) float f32x4;    // MFMA C/D

__device__ __forceinline__ float bf2f(u16 u) {
    return __uint_as_float(((u32)u) << 16);
}
__device__ __forceinline__ u16 f2bf(float f) {
    u32 u = __float_as_uint(f);
    u32 r = (u + 0x7fffu + ((u >> 16) & 1u)) >> 16;   // RNE
    return (u16)r;
}
// packed RNE f32x2 -> bf16x2; lo -> low 16 bits
__device__ __forceinline__ u32 pk2bf(float lo, float hi) {
    __hip_bfloat162 h = __float22bfloat162_rn(make_float2(lo, hi));
    union { __hip_bfloat162 h; u32 u; } cv; cv.h = h;
    return cv.u;
}
// packed bf16x2 multiply (RNE)
__device__ __forceinline__ u32 hmul2(u32 a, u32 b) {
    union { u32 u; __hip_bfloat162 h; } x, y, r;
    x.u = a; y.u = b;
    r.h = __hmul2(x.h, y.h);
    return r.u;
}
__device__ __forceinline__ float ldf(const void* p, size_t i, bool f32m) {
    return f32m ? ((const float*)p)[i] : bf2f(((const u16*)p)[i]);
}
// XOR-swizzled halfword index into a 64x128 bf16 LDS tile (16B-block swizzle).
__device__ __forceinline__ int swz(int row, int col) {
    return row * 128 + ((((col >> 3) ^ (row & 7)) << 3) | (col & 7));
}

// ---- dtype detector (parallel) ----
__global__ void detect_mode(const u32* __restrict__ x, int* __restrict__ mode) {
    __shared__ int cnt_s;
    if (threadIdx.x == 0) cnt_s = 0;
    __syncthreads();
    u32 e = (x[threadIdx.x] >> 23) & 0xFFu;
    if (e >= 90u && e < 170u) atomicAdd(&cnt_s, 1);
    __syncthreads();
    if (threadIdx.x == 0) mode[0] = (cnt_s >= 128) ? 1 : 0;
}

// ---- pack six 128x128 weight matrices into MFMA fragment order (bf16) ----
__global__ void pack_w6(const void* __restrict__ W0, const void* __restrict__ W1,
                        const void* __restrict__ W2, const void* __restrict__ W3,
                        const void* __restrict__ W4, const void* __restrict__ W5,
                        u16* __restrict__ out, const int* __restrict__ gmode) {
    const bool f32m = gmode[0] != 0;
    int gid = blockIdx.x * 256 + threadIdx.x;
    if (gid >= 6 * 16384) return;
    int sel = gid >> 14, idx = gid & 16383;
    const void* W = sel == 0 ? W0 : sel == 1 ? W1 : sel == 2 ? W2 :
                    sel == 3 ? W3 : sel == 4 ? W4 : W5;
    int j = idx & 7, lane = (idx >> 3) & 63, ks = (idx >> 9) & 3, nt = idx >> 11;
    int k = ks * 32 + (lane >> 4) * 8 + j;
    int n = nt * 16 + (lane & 15);
    out[gid] = f2bf(ldf(W, (size_t)k * HD + n, f32m));
}

// ================= CSR build ===========
__global__ void cnt_count(const int* __restrict__ dst, int* __restrict__ cnt, int e) {
    int i = blockIdx.x * 256 + threadIdx.x;
    if (i < e) atomicAdd(&cnt[dst[i]], 1);
}

__global__ void scan_blocks(const int* __restrict__ cnt, int* __restrict__ rowptr,
                            int* __restrict__ bsum, int n) {
    __shared__ int s[256];
    int t = threadIdx.x, gid = blockIdx.x * 256 + t;
    int v = (gid < n) ? cnt[gid] : 0;
    s[t] = v; __syncthreads();
    #pragma unroll
    for (int off = 1; off < 256; off <<= 1) {
        int x = (t >= off) ? s[t - off] : 0;
        __syncthreads();
        s[t] += x;
        __syncthreads();
    }
    if (gid < n) rowptr[gid] = s[t] - v;
    if (t == 255) bsum[blockIdx.x] = s[255];
}

__global__ void scan_bsum(int* __restrict__ bsum, int nb) {
    __shared__ int s[1024];
    __shared__ int carry;
    int t = threadIdx.x;
    if (t == 0) carry = 0;
    __syncthreads();
    for (int base = 0; base < nb; base += 1024) {
        int i = base + t;
        int v = (i < nb) ? bsum[i] : 0;
        s[t] = v; __syncthreads();
        #pragma unroll
        for (int off = 1; off < 1024; off <<= 1) {
            int x = (t >= off) ? s[t - off] : 0;
            __syncthreads();
            s[t] += x;
            __syncthreads();
        }
        if (i < nb) bsum[i] = carry + s[t] - v;
        __syncthreads();
        if (t == 0) carry += s[1023];
        __syncthreads();
    }
}

// rowptr finalize + cursor init (cur = rowptr)
__global__ void scan_add(int* __restrict__ rowptr, const int* __restrict__ bsum,
                         int* __restrict__ cur, int n, int e) {
    int gid = blockIdx.x * 256 + threadIdx.x;
    if (gid < n) {
        int v = rowptr[gid] + bsum[blockIdx.x];
        rowptr[gid] = v;
        cur[gid] = v;
    } else if (gid == n) {
        rowptr[n] = e;
    }
}

__global__ void csr_fill(const int* __restrict__ src, const int* __restrict__ dst,
                         int* __restrict__ cur, int* __restrict__ cidx, int e) {
    int i = blockIdx.x * 256 + threadIdx.x;
    if (i >= e) return;
    int p = atomicAdd(&cur[dst[i]], 1);
    cidx[p] = src[i];
}

// ---- CSR gather-aggregate -> bf16 mean; 16B/lane row segments ----
__global__ __launch_bounds__(256) void agg_gather(
    const void* __restrict__ h, const int* __restrict__ rowptr,
    const int* __restrict__ cidx, u16* __restrict__ aggb,
    const int* __restrict__ gmode, int use_mode, int n) {
    const bool f32m = use_mode && (gmode[0] != 0);
    int wid = (blockIdx.x * 256 + threadIdx.x) >> 6;
    int lane = threadIdx.x & 63;
    if (wid >= n) return;
    int l16 = lane & 15, g = lane >> 4;
    int s0 = rowptr[wid], s1 = rowptr[wid + 1];
    float acc[8] = {0.f, 0.f, 0.f, 0.f, 0.f, 0.f, 0.f, 0.f};
    for (int i = s0 + g; i < s1; i += 4) {
        int s = cidx[i];
        if (f32m) {
            const float* p = (const float*)h + (size_t)s * HD + l16 * 8;
            float4 a = *(const float4*)p, b = *(const float4*)(p + 4);
            acc[0] += a.x; acc[1] += a.y; acc[2] += a.z; acc[3] += a.w;
            acc[4] += b.x; acc[5] += b.y; acc[6] += b.z; acc[7] += b.w;
        } else {
            uint4 v = *(const uint4*)((const u16*)h + (size_t)s * HD + l16 * 8);
            acc[0] += __uint_as_float(v.x << 16); acc[1] += __uint_as_float(v.x & 0xffff0000u);
            acc[2] += __uint_as_float(v.y << 16); acc[3] += __uint_as_float(v.y & 0xffff0000u);
            acc[4] += __uint_as_float(v.z << 16); acc[5] += __uint_as_float(v.z & 0xffff0000u);
            acc[6] += __uint_as_float(v.w << 16); acc[7] += __uint_as_float(v.w & 0xffff0000u);
        }
    }
    #pragma unroll
    for (int k = 0; k < 8; k++) {
        acc[k] += __shfl_xor(acc[k], 16);
        acc[k] += __shfl_xor(acc[k], 32);
    }
    if (g == 0) {
        float iv = 1.f / fmaxf((float)(s1 - s0), 1.f);
        uint4 o;
        o.x = pk2bf(acc[0] * iv, acc[1] * iv);
        o.y = pk2bf(acc[2] * iv, acc[3] * iv);
        o.z = pk2bf(acc[4] * iv, acc[5] * iv);
        o.w = pk2bf(acc[6] * iv, acc[7] * iv);
        *(uint4*)&aggb[(size_t)wid * HD + l16 * 8] = o;
    }
}

// ---- MFMA SAGE layer, register-weights + grid-stride over node tiles ----
template <bool RELU>
__global__ __launch_bounds__(256) void sage_mfma(
    const void* __restrict__ X, const u16* __restrict__ aggb,
    const u16* __restrict__ Wsp, const u16* __restrict__ Wnp,
    const void* __restrict__ bias, u16* __restrict__ hout,
    const int* __restrict__ gmode, int use_mode, int n, int ntiles) {
    __shared__ u16 zS[64 * 128];
    __shared__ u16 zN[64 * 128];
    u16* outh = zS;

    const bool f32m = gmode[0] != 0;
    const bool inf32 = use_mode && f32m;
    const int t = threadIdx.x;
    const int lane = t & 63;
    const int w = t >> 6;
    const int cl = lane & 15, quad = lane >> 4;

    // ---- loop-invariant: weight A-frags + bias in registers ----
    short8 aS[2][4], aN[2][4];   // [ft][ks]
    f32x4 bv[2];
    #pragma unroll
    for (int ft = 0; ft < 2; ft++) {
        #pragma unroll
        for (int ks = 0; ks < 4; ks++) {
            aS[ft][ks] = ((const short8*)Wsp)[((w * 2 + ft) * 4 + ks) * 64 + lane];
            aN[ft][ks] = ((const short8*)Wnp)[((w * 2 + ft) * 4 + ks) * 64 + lane];
        }
        int f0 = w * 32 + ft * 16 + quad * 4;
        bv[ft][0] = ldf(bias, f0 + 0, f32m);
        bv[ft][1] = ldf(bias, f0 + 1, f32m);
        bv[ft][2] = ldf(bias, f0 + 2, f32m);
        bv[ft][3] = ldf(bias, f0 + 3, f32m);
    }

    for (int tile = blockIdx.x; tile < ntiles; tile += gridDim.x) {
        const int n0 = tile * 64;

        // ---- stage both tiles: 16 B/lane segments ----
        #pragma unroll
        for (int i = 0; i < 4; i++) {
            int idx = t + i * 256;
            int e = idx >> 4, sg = (idx & 15) * 8;
            int node = n0 + e;
            uint4 p = make_uint4(0, 0, 0, 0), q = make_uint4(0, 0, 0, 0);
            if (node < n) {
                if (inf32) {
                    const float* xp = (const float*)X + (size_t)node * HD + sg;
                    float4 v0 = *(const float4*)xp, v1 = *(const float4*)(xp + 4);
                    p.x = pk2bf(v0.x, v0.y); p.y = pk2bf(v0.z, v0.w);
                    p.z = pk2bf(v1.x, v1.y); p.w = pk2bf(v1.z, v1.w);
                } else {
                    p = *(const uint4*)((const u16*)X + (size_t)node * HD + sg);
                }
                q = *(const uint4*)&aggb[(size_t)node * HD + sg];
            }
            int sa = swz(e, sg);
            *(uint4*)&zS[sa] = p;
            *(uint4*)&zN[sa] = q;
        }
        __syncthreads();

        f32x4 acc[2][4];
        #pragma unroll
        for (int ft = 0; ft < 2; ft++)
            #pragma unroll
            for (int et = 0; et < 4; et++) acc[ft][et] = bv[ft];
        #pragma unroll
        for (int ks = 0; ks < 4; ks++) {
            short8 bS[4], bN[4];
            #pragma unroll
            for (int et = 0; et < 4; et++) {
                int sa = swz(et * 16 + cl, ks * 32 + quad * 8);
                bS[et] = *(const short8*)&zS[sa];
                bN[et] = *(const short8*)&zN[sa];
            }
            #pragma unroll
            for (int ft = 0; ft < 2; ft++)
                #pragma unroll
                for (int et = 0; et < 4; et++) {
                    acc[ft][et] = __builtin_amdgcn_mfma_f32_16x16x32_bf16(
                        aS[ft][ks], bS[et], acc[ft][et], 0, 0, 0);
                    acc[ft][et] = __builtin_amdgcn_mfma_f32_16x16x32_bf16(
                        aN[ft][ks], bN[et], acc[ft][et], 0, 0, 0);
                }
        }
        __syncthreads();

        // ---- epilogue ----
        #pragma unroll
        for (int ft = 0; ft < 2; ft++) {
            int f0 = w * 32 + ft * 16 + quad * 4;
            #pragma unroll
            for (int et = 0; et < 4; et++) {
                f32x4 v = acc[ft][et];
                float v0 = RELU ? fmaxf(v[0], 0.f) : v[0];
                float v1 = RELU ? fmaxf(v[1], 0.f) : v[1];
                float v2 = RELU ? fmaxf(v[2], 0.f) : v[2];
                float v3 = RELU ? fmaxf(v[3], 0.f) : v[3];
                *(uint2*)&outh[swz(et * 16 + cl, f0)] =
                    make_uint2(pk2bf(v0, v1), pk2bf(v2, v3));
            }
        }
        __syncthreads();
        #pragma unroll
        for (int i = 0; i < 4; i++) {
            int idx = t + i * 256;
            int e = idx >> 4, sg = (idx & 15) * 8;
            int node = n0 + e;
            if (node < n)
                *(uint4*)&hout[(size_t)node * HD + sg] = *(const uint4*)&outh[swz(e, sg)];
        }
        __syncthreads();   // outh (=zS) fully read before next tile's staging
    }
}

// ---- MFMA edge decoder: register weights, grid-stride over pos+neg tiles ----
__global__ __launch_bounds__(256) void edge_decode_mfma(
    const u16* __restrict__ h,
    const int* __restrict__ psrc, const int* __restrict__ pdst, int ep, int PB,
    const int* __restrict__ nsrc, const int* __restrict__ ndst, int en, int TB,
    const u16* __restrict__ W1p, const void* __restrict__ b1,
    const u16* __restrict__ W2p, const void* __restrict__ b2,
    const void* __restrict__ W3, const void* __restrict__ b3,
    void* __restrict__ out, const int* __restrict__ gmode) {
    __shared__ u16 zA[64 * 128];
    __shared__ u16 zB[64 * 128];
    __shared__ float psum[256];
    const bool f32m = gmode[0] != 0;
    const int t = threadIdx.x;
    const int lane = t & 63;
    const int w = t >> 6;
    const int cl = lane & 15, quad = lane >> 4;

    // ---- loop-invariant: W1/W2 A-frags, biases, W3 in registers ----
    short8 w1f[2][4], w2f[2][4];
    f32x4 bv1[2], bv2[2], w3v[2];
    #pragma unroll
    for (int ft = 0; ft < 2; ft++) {
        #pragma unroll
        for (int ks = 0; ks < 4; ks++) {
            w1f[ft][ks] = ((const short8*)W1p)[((w * 2 + ft) * 4 + ks) * 64 + lane];
            w2f[ft][ks] = ((const short8*)W2p)[((w * 2 + ft) * 4 + ks) * 64 + lane];
        }
        int f0 = w * 32 + ft * 16 + quad * 4;
        #pragma unroll
        for (int r = 0; r < 4; r++) {
            bv1[ft][r] = ldf(b1, f0 + r, f32m);
            bv2[ft][r] = ldf(b2, f0 + r, f32m);
            w3v[ft][r] = ldf(W3, f0 + r, f32m);
        }
    }
    const float b3v = ldf(b3, 0, f32m);

    for (int tile = blockIdx.x; tile < TB; tile += gridDim.x) {
        const int* esrc; const int* edst; int e0, obase, ne;
        if (tile < PB) { esrc = psrc; edst = pdst; e0 = tile * 64;        obase = 0;  ne = ep; }
        else           { esrc = nsrc; edst = ndst; e0 = (tile - PB) * 64; obase = ep; ne = en; }

        // ---- stage z0 = bf16(h[s]*h[d]): 16 B/lane, packed bf16 mul ----
        #pragma unroll
        for (int i = 0; i < 4; i++) {
            int idx = t + i * 256;
            int e = idx >> 4, sg = (idx & 15) * 8;
            int eg = e0 + e;
            uint4 z = make_uint4(0, 0, 0, 0);
            if (eg < ne) {
                int s = esrc[eg], d = edst[eg];
                uint4 a  = *(const uint4*)(h + (size_t)s * HD + sg);
                uint4 bb = *(const uint4*)(h + (size_t)d * HD + sg);
                z.x = hmul2(a.x, bb.x); z.y = hmul2(a.y, bb.y);
                z.z = hmul2(a.z, bb.z); z.w = hmul2(a.w, bb.w);
            }
            *(uint4*)&zA[swz(e, sg)] = z;
        }
        __syncthreads();

        // ---- gemm1: z1 = relu(z0@W1+b1) -> zB ----
        {
            f32x4 acc[2][4];
            #pragma unroll
            for (int ft = 0; ft < 2; ft++)
                #pragma unroll
                for (int et = 0; et < 4; et++) acc[ft][et] = bv1[ft];
            #pragma unroll
            for (int ks = 0; ks < 4; ks++) {
                short8 b[4];
                #pragma unroll
                for (int et = 0; et < 4; et++)
                    b[et] = *(const short8*)&zA[swz(et * 16 + cl, ks * 32 + quad * 8)];
                #pragma unroll
                for (int ft = 0; ft < 2; ft++)
                    #pragma unroll
                    for (int et = 0; et < 4; et++)
                        acc[ft][et] = __builtin_amdgcn_mfma_f32_16x16x32_bf16(
                            w1f[ft][ks], b[et], acc[ft][et], 0, 0, 0);
            }
            #pragma unroll
            for (int ft = 0; ft < 2; ft++) {
                int f0 = w * 32 + ft * 16 + quad * 4;
                #pragma unroll
                for (int et = 0; et < 4; et++) {
                    f32x4 v = acc[ft][et];
                    *(uint2*)&zB[swz(et * 16 + cl, f0)] = make_uint2(
                        pk2bf(fmaxf(v[0], 0.f), fmaxf(v[1], 0.f)),
                        pk2bf(fmaxf(v[2], 0.f), fmaxf(v[3], 0.f)));
                }
            }
        }
        __syncthreads();

        // ---- gemm2 in registers + W3 dot ----
        f32x4 acc[2][4];
        #pragma unroll
        for (int ft = 0; ft < 2; ft++)
            #pragma unroll
            for (int et = 0; et < 4; et++) acc[ft][et] = bv2[ft];
        #pragma unroll
        for (int ks = 0; ks < 4; ks++) {
            short8 bb[4];
            #pragma unroll
            for (int et = 0; et < 4; et++)
                bb[et] = *(const short8*)&zB[swz(et * 16 + cl, ks * 32 + quad * 8)];
            #pragma unroll
            for (int ft = 0; ft < 2; ft++)
                #pragma unroll
                for (int et = 0; et < 4; et++)
                    acc[ft][et] = __builtin_amdgcn_mfma_f32_16x16x32_bf16(
                        w2f[ft][ks], bb[et], acc[ft][et], 0, 0, 0);
        }
        float p[4] = {0.f, 0.f, 0.f, 0.f};
        #pragma unroll
        for (int ft = 0; ft < 2; ft++)
            #pragma unroll
            for (int et = 0; et < 4; et++) {
                f32x4 v = acc[ft][et];
                p[et] = fmaf(fmaxf(v[0], 0.f), w3v[ft][0], p[et]);
                p[et] = fmaf(fmaxf(v[1], 0.f), w3v[ft][1], p[et]);
                p[et] = fmaf(fmaxf(v[2], 0.f), w3v[ft][2], p[et]);
                p[et] = fmaf(fmaxf(v[3], 0.f), w3v[ft][3], p[et]);
            }
        #pragma unroll
        for (int et = 0; et < 4; et++) {
            p[et] += __shfl_xor(p[et], 16);
            p[et] += __shfl_xor(p[et], 32);
        }
        if (lane < 16) {
            #pragma unroll
            for (int et = 0; et < 4; et++)
                psum[w * 64 + et * 16 + lane] = p[et];
        }
        __syncthreads();
        if (t < 64) {
            int eg = e0 + t;
            if (eg < ne) {
                float sum = b3v + (psum[t] + psum[64 + t]) + (psum[128 + t] + psum[192 + t]);
                if (f32m) ((float*)out)[obase + eg] = sum;
                else      ((u16*)out)[obase + eg]   = f2bf(sum);
            }
        }
        __syncthreads();   // psum fully read before next tile overwrites
    }
}

extern "C" void kernel_launch(void* const* d_in, const int* in_sizes, int n_in,
                              void* d_out, int out_size, void* d_ws, size_t ws_size,
                              hipStream_t stream) {
    const void* x      = d_in[0];
    const int* src     = (const int*)d_in[1];
    const int* dst     = (const int*)d_in[2];
    const int* pos_src = (const int*)d_in[3];
    const int* pos_dst = (const int*)d_in[4];
    const int* neg_src = (const int*)d_in[5];
    const int* neg_dst = (const int*)d_in[6];
    const void* Ws0 = d_in[7];
    const void* Wn0 = d_in[8];
    const void* b0  = d_in[9];
    const void* Ws1 = d_in[10];
    const void* Wn1 = d_in[11];
    const void* b1  = d_in[12];
    const void* dW1 = d_in[13];
    const void* db1 = d_in[14];
    const void* dW2 = d_in[15];
    const void* db2 = d_in[16];
    const void* dW3 = d_in[17];
    const void* db3 = d_in[18];

    const int n  = in_sizes[0] / HD;
    const int e  = in_sizes[1];
    const int ep = in_sizes[3];
    const int en = in_sizes[5];
    const int NB = (n + 255) / 256;
    const int PB = (ep + 63) / 64, NDB = (en + 63) / 64;
    const int NT = (n + 63) / 64;

    // ws: aggb/h2[n*HD] u16 | h1[n*HD] u16 | mode | rowptr | cur | cidx | bsum | packed W x6
    char* base = (char*)d_ws;
    u16* aggb = (u16*)d_ws;              // doubles as h2 (tile-private rows)
    u16* h1   = aggb + (size_t)n * HD;
    size_t off = (size_t)n * HD * 4;
    int* mode = (int*)(base + off);      off += 16;
    int* rowptr = (int*)(base + off);    off += (size_t)(n + 1) * 4; off = (off + 15) & ~(size_t)15;
    int* cur = (int*)(base + off);       off += (size_t)n * 4;       off = (off + 15) & ~(size_t)15;
    int* cidx = (int*)(base + off);      off += (size_t)e * 4;       off = (off + 15) & ~(size_t)15;
    int* bsum = (int*)(base + off);      off += (size_t)NB * 4;      off = (off + 15) & ~(size_t)15;
    u16* Wpk  = (u16*)(base + off);      // order: dW1, dW2, Ws0, Wn0, Ws1, Wn1
    u16* W1p  = Wpk;
    u16* W2p  = Wpk + 16384;
    u16* Ws0p = Wpk + 2 * 16384;
    u16* Wn0p = Wpk + 3 * 16384;
    u16* Ws1p = Wpk + 4 * 16384;
    u16* Wn1p = Wpk + 5 * 16384;

    detect_mode<<<dim3(1), dim3(256), 0, stream>>>((const u32*)x, mode);

    // ---- CSR build (once) ----
    hipMemsetAsync(cur, 0, (size_t)n * 4, stream);   // cur doubles as cnt
    cnt_count<<<dim3((e + 255) / 256), dim3(256), 0, stream>>>(dst, cur, e);
    scan_blocks<<<dim3(NB), dim3(256), 0, stream>>>(cur, rowptr, bsum, n);
    scan_bsum<<<dim3(1), dim3(1024), 0, stream>>>(bsum, NB);
    scan_add<<<dim3((n + 256) / 256), dim3(256), 0, stream>>>(rowptr, bsum, cur, n, e);
    csr_fill<<<dim3((e + 255) / 256), dim3(256), 0, stream>>>(src, dst, cur, cidx, e);

    pack_w6<<<dim3(384), dim3(256), 0, stream>>>(dW1, dW2, Ws0, Wn0, Ws1, Wn1, Wpk, mode);

    // ---- layer 0: h1 = relu(x@Ws0 + mean@Wn0 + b0) ----
    agg_gather<<<dim3((n * 64 + 255) / 256), dim3(256), 0, stream>>>(
        x, rowptr, cidx, aggb, mode, 1, n);
    sage_mfma<true><<<dim3(1024), dim3(256), 0, stream>>>(
        x, aggb, Ws0p, Wn0p, b0, h1, mode, 1, n, NT);

    // ---- layer 1: h2 = h1@Ws1 + mean(h1)@Wn1 + b1  (h2 aliases aggb) ----
    agg_gather<<<dim3((n * 64 + 255) / 256), dim3(256), 0, stream>>>(
        h1, rowptr, cidx, aggb, mode, 0, n);
    sage_mfma<false><<<dim3(1024), dim3(256), 0, stream>>>(
        h1, aggb, Ws1p, Wn1p, b1, aggb /*h2 in-place*/, mode, 0, n, NT);

    // ---- fused pos+neg decoder on h2 (bf16), grid-stride ----
    int TB = PB + NDB;
    int db = TB < 1024 ? TB : 1024;
    edge_decode_mfma<<<dim3(db), dim3(256), 0, stream>>>(
        aggb, pos_src, pos_dst, ep, PB, neg_src, neg_dst, en, TB,
        W1p, db1, W2p, db2, dW3, db3, d_out, mode);
}

// Round 12
// 364.904 us; speedup vs baseline: 1.0925x; 1.0925x over previous
//
#include <hip/hip_runtime.h>
#include <hip/hip_bf16.h>

#define HD 128

typedef unsigned int u32;
typedef unsigned short u16;
typedef __attribute__((ext_vector_type(8))) short short8;   // 8 bf16 (4 VGPRs)
typedef __attribute__((ext_vector_type(4))) float f32x4;    // MFMA C/D

__device__ __forceinline__ float bf2f(u16 u) {
    return __uint_as_float(((u32)u) << 16);
}
__device__ __forceinline__ u16 f2bf(float f) {
    u32 u = __float_as_uint(f);
    u32 r = (u + 0x7fffu + ((u >> 16) & 1u)) >> 16;   // RNE
    return (u16)r;
}
// packed RNE f32x2 -> bf16x2; lo -> low 16 bits
__device__ __forceinline__ u32 pk2bf(float lo, float hi) {
    __hip_bfloat162 h = __float22bfloat162_rn(make_float2(lo, hi));
    union { __hip_bfloat162 h; u32 u; } cv; cv.h = h;
    return cv.u;
}
// packed bf16x2 multiply (RNE)
__device__ __forceinline__ u32 hmul2(u32 a, u32 b) {
    union { u32 u; __hip_bfloat162 h; } x, y, r;
    x.u = a; y.u = b;
    r.h = __hmul2(x.h, y.h);
    return r.u;
}
__device__ __forceinline__ float ldf(const void* p, size_t i, bool f32m) {
    return f32m ? ((const float*)p)[i] : bf2f(((const u16*)p)[i]);
}
// XOR-swizzled halfword index into a 64x128 bf16 LDS tile (16B-block swizzle).
__device__ __forceinline__ int swz(int row, int col) {
    return row * 128 + ((((col >> 3) ^ (row & 7)) << 3) | (col & 7));
}

// ---- dtype detector (parallel) ----
__global__ void detect_mode(const u32* __restrict__ x, int* __restrict__ mode) {
    __shared__ int cnt_s;
    if (threadIdx.x == 0) cnt_s = 0;
    __syncthreads();
    u32 e = (x[threadIdx.x] >> 23) & 0xFFu;
    if (e >= 90u && e < 170u) atomicAdd(&cnt_s, 1);
    __syncthreads();
    if (threadIdx.x == 0) mode[0] = (cnt_s >= 128) ? 1 : 0;
}

// ---- pack six 128x128 weight matrices into MFMA fragment order (bf16) ----
__global__ void pack_w6(const void* __restrict__ W0, const void* __restrict__ W1,
                        const void* __restrict__ W2, const void* __restrict__ W3,
                        const void* __restrict__ W4, const void* __restrict__ W5,
                        u16* __restrict__ out, const int* __restrict__ gmode) {
    const bool f32m = gmode[0] != 0;
    int gid = blockIdx.x * 256 + threadIdx.x;
    if (gid >= 6 * 16384) return;
    int sel = gid >> 14, idx = gid & 16383;
    const void* W = sel == 0 ? W0 : sel == 1 ? W1 : sel == 2 ? W2 :
                    sel == 3 ? W3 : sel == 4 ? W4 : W5;
    int j = idx & 7, lane = (idx >> 3) & 63, ks = (idx >> 9) & 3, nt = idx >> 11;
    int k = ks * 32 + (lane >> 4) * 8 + j;
    int n = nt * 16 + (lane & 15);
    out[gid] = f2bf(ldf(W, (size_t)k * HD + n, f32m));
}

// ================= CSR build ===========
__global__ void cnt_count(const int* __restrict__ dst, int* __restrict__ cnt, int e) {
    int i = blockIdx.x * 256 + threadIdx.x;
    if (i < e) atomicAdd(&cnt[dst[i]], 1);
}

__global__ void scan_blocks(const int* __restrict__ cnt, int* __restrict__ rowptr,
                            int* __restrict__ bsum, int n) {
    __shared__ int s[256];
    int t = threadIdx.x, gid = blockIdx.x * 256 + t;
    int v = (gid < n) ? cnt[gid] : 0;
    s[t] = v; __syncthreads();
    #pragma unroll
    for (int off = 1; off < 256; off <<= 1) {
        int x = (t >= off) ? s[t - off] : 0;
        __syncthreads();
        s[t] += x;
        __syncthreads();
    }
    if (gid < n) rowptr[gid] = s[t] - v;
    if (t == 255) bsum[blockIdx.x] = s[255];
}

__global__ void scan_bsum(int* __restrict__ bsum, int nb) {
    __shared__ int s[1024];
    __shared__ int carry;
    int t = threadIdx.x;
    if (t == 0) carry = 0;
    __syncthreads();
    for (int base = 0; base < nb; base += 1024) {
        int i = base + t;
        int v = (i < nb) ? bsum[i] : 0;
        s[t] = v; __syncthreads();
        #pragma unroll
        for (int off = 1; off < 1024; off <<= 1) {
            int x = (t >= off) ? s[t - off] : 0;
            __syncthreads();
            s[t] += x;
            __syncthreads();
        }
        if (i < nb) bsum[i] = carry + s[t] - v;
        __syncthreads();
        if (t == 0) carry += s[1023];
        __syncthreads();
    }
}

// rowptr finalize + cursor init (cur = rowptr)
__global__ void scan_add(int* __restrict__ rowptr, const int* __restrict__ bsum,
                         int* __restrict__ cur, int n, int e) {
    int gid = blockIdx.x * 256 + threadIdx.x;
    if (gid < n) {
        int v = rowptr[gid] + bsum[blockIdx.x];
        rowptr[gid] = v;
        cur[gid] = v;
    } else if (gid == n) {
        rowptr[n] = e;
    }
}

__global__ void csr_fill(const int* __restrict__ src, const int* __restrict__ dst,
                         int* __restrict__ cur, int* __restrict__ cidx, int e) {
    int i = blockIdx.x * 256 + threadIdx.x;
    if (i >= e) return;
    int p = atomicAdd(&cur[dst[i]], 1);
    cidx[p] = src[i];
}

// ---- CSR gather-aggregate -> bf16 mean; 16B/lane row segments ----
__global__ __launch_bounds__(256) void agg_gather(
    const void* __restrict__ h, const int* __restrict__ rowptr,
    const int* __restrict__ cidx, u16* __restrict__ aggb,
    const int* __restrict__ gmode, int use_mode, int n) {
    const bool f32m = use_mode && (gmode[0] != 0);
    int wid = (blockIdx.x * 256 + threadIdx.x) >> 6;
    int lane = threadIdx.x & 63;
    if (wid >= n) return;
    int l16 = lane & 15, g = lane >> 4;
    int s0 = rowptr[wid], s1 = rowptr[wid + 1];
    float acc[8] = {0.f, 0.f, 0.f, 0.f, 0.f, 0.f, 0.f, 0.f};
    for (int i = s0 + g; i < s1; i += 4) {
        int s = cidx[i];
        if (f32m) {
            const float* p = (const float*)h + (size_t)s * HD + l16 * 8;
            float4 a = *(const float4*)p, b = *(const float4*)(p + 4);
            acc[0] += a.x; acc[1] += a.y; acc[2] += a.z; acc[3] += a.w;
            acc[4] += b.x; acc[5] += b.y; acc[6] += b.z; acc[7] += b.w;
        } else {
            uint4 v = *(const uint4*)((const u16*)h + (size_t)s * HD + l16 * 8);
            acc[0] += __uint_as_float(v.x << 16); acc[1] += __uint_as_float(v.x & 0xffff0000u);
            acc[2] += __uint_as_float(v.y << 16); acc[3] += __uint_as_float(v.y & 0xffff0000u);
            acc[4] += __uint_as_float(v.z << 16); acc[5] += __uint_as_float(v.z & 0xffff0000u);
            acc[6] += __uint_as_float(v.w << 16); acc[7] += __uint_as_float(v.w & 0xffff0000u);
        }
    }
    #pragma unroll
    for (int k = 0; k < 8; k++) {
        acc[k] += __shfl_xor(acc[k], 16);
        acc[k] += __shfl_xor(acc[k], 32);
    }
    if (g == 0) {
        float iv = 1.f / fmaxf((float)(s1 - s0), 1.f);
        uint4 o;
        o.x = pk2bf(acc[0] * iv, acc[1] * iv);
        o.y = pk2bf(acc[2] * iv, acc[3] * iv);
        o.z = pk2bf(acc[4] * iv, acc[5] * iv);
        o.w = pk2bf(acc[6] * iv, acc[7] * iv);
        *(uint4*)&aggb[(size_t)wid * HD + l16 * 8] = o;
    }
}

// ---- MFMA SAGE layer: ONE 16 KB tile, two passes (self then neighbor) ----
// LDS 16.4 KB -> 8 blocks/CU (was 4 at 33 KB). Latency-bound: occupancy wins.
template <bool RELU>
__global__ __launch_bounds__(256) void sage_mfma(
    const void* __restrict__ X, const u16* __restrict__ aggb,
    const u16* __restrict__ Wsp, const u16* __restrict__ Wnp,
    const void* __restrict__ bias, u16* __restrict__ hout,
    const int* __restrict__ gmode, int use_mode, int n) {
    __shared__ u16 z[64 * 128];   // swizzled tile, 16 KB
    const bool f32m = gmode[0] != 0;
    const bool inf32 = use_mode && f32m;
    const int t = threadIdx.x;
    const int n0 = blockIdx.x * 64;
    const int lane = t & 63;
    const int w = t >> 6;
    const int cl = lane & 15, quad = lane >> 4;

    // ---- pass A: stage X tile ----
    #pragma unroll
    for (int i = 0; i < 4; i++) {
        int idx = t + i * 256;
        int e = idx >> 4, sg = (idx & 15) * 8;
        int node = n0 + e;
        uint4 p = make_uint4(0, 0, 0, 0);
        if (node < n) {
            if (inf32) {
                const float* xp = (const float*)X + (size_t)node * HD + sg;
                float4 v0 = *(const float4*)xp, v1 = *(const float4*)(xp + 4);
                p.x = pk2bf(v0.x, v0.y); p.y = pk2bf(v0.z, v0.w);
                p.z = pk2bf(v1.x, v1.y); p.w = pk2bf(v1.z, v1.w);
            } else {
                p = *(const uint4*)((const u16*)X + (size_t)node * HD + sg);
            }
        }
        *(uint4*)&z[swz(e, sg)] = p;
    }
    __syncthreads();

    f32x4 acc[2][4];
    #pragma unroll
    for (int ft = 0; ft < 2; ft++) {
        int f0 = w * 32 + ft * 16 + quad * 4;
        f32x4 bv;
        bv[0] = ldf(bias, f0 + 0, f32m);
        bv[1] = ldf(bias, f0 + 1, f32m);
        bv[2] = ldf(bias, f0 + 2, f32m);
        bv[3] = ldf(bias, f0 + 3, f32m);
        #pragma unroll
        for (int et = 0; et < 4; et++) acc[ft][et] = bv;
    }
    #pragma unroll
    for (int ks = 0; ks < 4; ks++) {
        short8 a[2], b[4];
        #pragma unroll
        for (int ft = 0; ft < 2; ft++)
            a[ft] = ((const short8*)Wsp)[((w * 2 + ft) * 4 + ks) * 64 + lane];
        #pragma unroll
        for (int et = 0; et < 4; et++)
            b[et] = *(const short8*)&z[swz(et * 16 + cl, ks * 32 + quad * 8)];
        #pragma unroll
        for (int ft = 0; ft < 2; ft++)
            #pragma unroll
            for (int et = 0; et < 4; et++)
                acc[ft][et] = __builtin_amdgcn_mfma_f32_16x16x32_bf16(
                    a[ft], b[et], acc[ft][et], 0, 0, 0);
    }
    __syncthreads();   // all reads of X tile done

    // ---- pass B: stage neighbor-mean tile into same buffer ----
    #pragma unroll
    for (int i = 0; i < 4; i++) {
        int idx = t + i * 256;
        int e = idx >> 4, sg = (idx & 15) * 8;
        int node = n0 + e;
        uint4 q = make_uint4(0, 0, 0, 0);
        if (node < n) q = *(const uint4*)&aggb[(size_t)node * HD + sg];
        *(uint4*)&z[swz(e, sg)] = q;
    }
    __syncthreads();
    #pragma unroll
    for (int ks = 0; ks < 4; ks++) {
        short8 a[2], b[4];
        #pragma unroll
        for (int ft = 0; ft < 2; ft++)
            a[ft] = ((const short8*)Wnp)[((w * 2 + ft) * 4 + ks) * 64 + lane];
        #pragma unroll
        for (int et = 0; et < 4; et++)
            b[et] = *(const short8*)&z[swz(et * 16 + cl, ks * 32 + quad * 8)];
        #pragma unroll
        for (int ft = 0; ft < 2; ft++)
            #pragma unroll
            for (int et = 0; et < 4; et++)
                acc[ft][et] = __builtin_amdgcn_mfma_f32_16x16x32_bf16(
                    a[ft], b[et], acc[ft][et], 0, 0, 0);
    }
    __syncthreads();   // all reads done before epilogue aliasing

    // ---- epilogue: packed b64 swizzled LDS writes, coalesced global copy ----
    #pragma unroll
    for (int ft = 0; ft < 2; ft++) {
        int f0 = w * 32 + ft * 16 + quad * 4;
        #pragma unroll
        for (int et = 0; et < 4; et++) {
            f32x4 v = acc[ft][et];
            float v0 = RELU ? fmaxf(v[0], 0.f) : v[0];
            float v1 = RELU ? fmaxf(v[1], 0.f) : v[1];
            float v2 = RELU ? fmaxf(v[2], 0.f) : v[2];
            float v3 = RELU ? fmaxf(v[3], 0.f) : v[3];
            *(uint2*)&z[swz(et * 16 + cl, f0)] =
                make_uint2(pk2bf(v0, v1), pk2bf(v2, v3));
        }
    }
    __syncthreads();
    #pragma unroll
    for (int i = 0; i < 4; i++) {
        int idx = t + i * 256;
        int e = idx >> 4, sg = (idx & 15) * 8;
        int node = n0 + e;
        if (node < n)
            *(uint4*)&hout[(size_t)node * HD + sg] = *(const uint4*)&z[swz(e, sg)];
    }
}

// ---- MFMA edge decoder, pos+neg fused; ONE tile (17.4 KB -> 8 blocks/CU) ----
__global__ __launch_bounds__(256) void edge_decode_mfma(
    const u16* __restrict__ h,
    const int* __restrict__ psrc, const int* __restrict__ pdst, int ep, int PB,
    const int* __restrict__ nsrc, const int* __restrict__ ndst, int en,
    const u16* __restrict__ W1p, const void* __restrict__ b1,
    const u16* __restrict__ W2p, const void* __restrict__ b2,
    const void* __restrict__ W3, const void* __restrict__ b3,
    void* __restrict__ out, const int* __restrict__ gmode) {
    __shared__ u16 zA[64 * 128];
    __shared__ float psum[256];
    const bool f32m = gmode[0] != 0;
    const int t = threadIdx.x;
    const int b = blockIdx.x;
    const int* esrc; const int* edst; int e0, obase, ne;
    if (b < PB) { esrc = psrc; edst = pdst; e0 = b * 64;        obase = 0;  ne = ep; }
    else        { esrc = nsrc; edst = ndst; e0 = (b - PB) * 64; obase = ep; ne = en; }
    const int lane = t & 63;
    const int w = t >> 6;
    const int cl = lane & 15, quad = lane >> 4;

    // ---- stage z0 = bf16(h[s]*h[d]): 16 B/lane, packed bf16 mul ----
    #pragma unroll
    for (int i = 0; i < 4; i++) {
        int idx = t + i * 256;
        int e = idx >> 4, sg = (idx & 15) * 8;
        int eg = e0 + e;
        uint4 z = make_uint4(0, 0, 0, 0);
        if (eg < ne) {
            int s = esrc[eg], d = edst[eg];
            uint4 a  = *(const uint4*)(h + (size_t)s * HD + sg);
            uint4 bv = *(const uint4*)(h + (size_t)d * HD + sg);
            z.x = hmul2(a.x, bv.x); z.y = hmul2(a.y, bv.y);
            z.z = hmul2(a.z, bv.z); z.w = hmul2(a.w, bv.w);
        }
        *(uint4*)&zA[swz(e, sg)] = z;
    }
    __syncthreads();

    // ---- gemm1: acc in registers ----
    f32x4 acc[2][4];
    #pragma unroll
    for (int ft = 0; ft < 2; ft++) {
        int f0 = w * 32 + ft * 16 + quad * 4;
        f32x4 bv;
        bv[0] = ldf(b1, f0 + 0, f32m);
        bv[1] = ldf(b1, f0 + 1, f32m);
        bv[2] = ldf(b1, f0 + 2, f32m);
        bv[3] = ldf(b1, f0 + 3, f32m);
        #pragma unroll
        for (int et = 0; et < 4; et++) acc[ft][et] = bv;
    }
    #pragma unroll
    for (int ks = 0; ks < 4; ks++) {
        short8 a[2], bb[4];
        #pragma unroll
        for (int ft = 0; ft < 2; ft++)
            a[ft] = ((const short8*)W1p)[((w * 2 + ft) * 4 + ks) * 64 + lane];
        #pragma unroll
        for (int et = 0; et < 4; et++)
            bb[et] = *(const short8*)&zA[swz(et * 16 + cl, ks * 32 + quad * 8)];
        #pragma unroll
        for (int ft = 0; ft < 2; ft++)
            #pragma unroll
            for (int et = 0; et < 4; et++)
                acc[ft][et] = __builtin_amdgcn_mfma_f32_16x16x32_bf16(
                    a[ft], bb[et], acc[ft][et], 0, 0, 0);
    }
    __syncthreads();   // all reads of z0 done

    // ---- write relu(z1) back into the SAME tile ----
    #pragma unroll
    for (int ft = 0; ft < 2; ft++) {
        int f0 = w * 32 + ft * 16 + quad * 4;
        #pragma unroll
        for (int et = 0; et < 4; et++) {
            f32x4 v = acc[ft][et];
            *(uint2*)&zA[swz(et * 16 + cl, f0)] = make_uint2(
                pk2bf(fmaxf(v[0], 0.f), fmaxf(v[1], 0.f)),
                pk2bf(fmaxf(v[2], 0.f), fmaxf(v[3], 0.f)));
        }
    }
    __syncthreads();

    // ---- gemm2 in registers + W3 dot ----
    #pragma unroll
    for (int ft = 0; ft < 2; ft++) {
        int f0 = w * 32 + ft * 16 + quad * 4;
        f32x4 bv;
        bv[0] = ldf(b2, f0 + 0, f32m);
        bv[1] = ldf(b2, f0 + 1, f32m);
        bv[2] = ldf(b2, f0 + 2, f32m);
        bv[3] = ldf(b2, f0 + 3, f32m);
        #pragma unroll
        for (int et = 0; et < 4; et++) acc[ft][et] = bv;
    }
    #pragma unroll
    for (int ks = 0; ks < 4; ks++) {
        short8 a[2], bb[4];
        #pragma unroll
        for (int ft = 0; ft < 2; ft++)
            a[ft] = ((const short8*)W2p)[((w * 2 + ft) * 4 + ks) * 64 + lane];
        #pragma unroll
        for (int et = 0; et < 4; et++)
            bb[et] = *(const short8*)&zA[swz(et * 16 + cl, ks * 32 + quad * 8)];
        #pragma unroll
        for (int ft = 0; ft < 2; ft++)
            #pragma unroll
            for (int et = 0; et < 4; et++)
                acc[ft][et] = __builtin_amdgcn_mfma_f32_16x16x32_bf16(
                    a[ft], bb[et], acc[ft][et], 0, 0, 0);
    }
    // per-lane partial dot of relu(z2) with W3 over this lane's 8 feats
    float p[4] = {0.f, 0.f, 0.f, 0.f};
    #pragma unroll
    for (int ft = 0; ft < 2; ft++) {
        int f0 = w * 32 + ft * 16 + quad * 4;
        float w3v0 = ldf(W3, f0 + 0, f32m);
        float w3v1 = ldf(W3, f0 + 1, f32m);
        float w3v2 = ldf(W3, f0 + 2, f32m);
        float w3v3 = ldf(W3, f0 + 3, f32m);
        #pragma unroll
        for (int et = 0; et < 4; et++) {
            f32x4 v = acc[ft][et];
            p[et] = fmaf(fmaxf(v[0], 0.f), w3v0, p[et]);
            p[et] = fmaf(fmaxf(v[1], 0.f), w3v1, p[et]);
            p[et] = fmaf(fmaxf(v[2], 0.f), w3v2, p[et]);
            p[et] = fmaf(fmaxf(v[3], 0.f), w3v3, p[et]);
        }
    }
    #pragma unroll
    for (int et = 0; et < 4; et++) {
        p[et] += __shfl_xor(p[et], 16);
        p[et] += __shfl_xor(p[et], 32);
    }
    if (lane < 16) {
        #pragma unroll
        for (int et = 0; et < 4; et++)
            psum[w * 64 + et * 16 + lane] = p[et];
    }
    __syncthreads();
    if (t < 64) {
        int eg = e0 + t;
        if (eg < ne) {
            float sum = ldf(b3, 0, f32m) + (psum[t] + psum[64 + t])
                      + (psum[128 + t] + psum[192 + t]);
            if (f32m) ((float*)out)[obase + eg] = sum;
            else      ((u16*)out)[obase + eg]   = f2bf(sum);
        }
    }
}

extern "C" void kernel_launch(void* const* d_in, const int* in_sizes, int n_in,
                              void* d_out, int out_size, void* d_ws, size_t ws_size,
                              hipStream_t stream) {
    const void* x      = d_in[0];
    const int* src     = (const int*)d_in[1];
    const int* dst     = (const int*)d_in[2];
    const int* pos_src = (const int*)d_in[3];
    const int* pos_dst = (const int*)d_in[4];
    const int* neg_src = (const int*)d_in[5];
    const int* neg_dst = (const int*)d_in[6];
    const void* Ws0 = d_in[7];
    const void* Wn0 = d_in[8];
    const void* b0  = d_in[9];
    const void* Ws1 = d_in[10];
    const void* Wn1 = d_in[11];
    const void* b1  = d_in[12];
    const void* dW1 = d_in[13];
    const void* db1 = d_in[14];
    const void* dW2 = d_in[15];
    const void* db2 = d_in[16];
    const void* dW3 = d_in[17];
    const void* db3 = d_in[18];

    const int n  = in_sizes[0] / HD;
    const int e  = in_sizes[1];
    const int ep = in_sizes[3];
    const int en = in_sizes[5];
    const int NB = (n + 255) / 256;
    const int PB = (ep + 63) / 64, NDB = (en + 63) / 64;

    // ws: aggb/h2[n*HD] u16 | h1[n*HD] u16 | mode | rowptr | cur | cidx | bsum | packed W x6
    char* base = (char*)d_ws;
    u16* aggb = (u16*)d_ws;              // doubles as h2 (block-private rows)
    u16* h1   = aggb + (size_t)n * HD;
    size_t off = (size_t)n * HD * 4;
    int* mode = (int*)(base + off);      off += 16;
    int* rowptr = (int*)(base + off);    off += (size_t)(n + 1) * 4; off = (off + 15) & ~(size_t)15;
    int* cur = (int*)(base + off);       off += (size_t)n * 4;       off = (off + 15) & ~(size_t)15;
    int* cidx = (int*)(base + off);      off += (size_t)e * 4;       off = (off + 15) & ~(size_t)15;
    int* bsum = (int*)(base + off);      off += (size_t)NB * 4;      off = (off + 15) & ~(size_t)15;
    u16* Wpk  = (u16*)(base + off);      // order: dW1, dW2, Ws0, Wn0, Ws1, Wn1
    u16* W1p  = Wpk;
    u16* W2p  = Wpk + 16384;
    u16* Ws0p = Wpk + 2 * 16384;
    u16* Wn0p = Wpk + 3 * 16384;
    u16* Ws1p = Wpk + 4 * 16384;
    u16* Wn1p = Wpk + 5 * 16384;

    detect_mode<<<dim3(1), dim3(256), 0, stream>>>((const u32*)x, mode);

    // ---- CSR build (once) ----
    hipMemsetAsync(cur, 0, (size_t)n * 4, stream);   // cur doubles as cnt
    cnt_count<<<dim3((e + 255) / 256), dim3(256), 0, stream>>>(dst, cur, e);
    scan_blocks<<<dim3(NB), dim3(256), 0, stream>>>(cur, rowptr, bsum, n);
    scan_bsum<<<dim3(1), dim3(1024), 0, stream>>>(bsum, NB);
    scan_add<<<dim3((n + 256) / 256), dim3(256), 0, stream>>>(rowptr, bsum, cur, n, e);
    csr_fill<<<dim3((e + 255) / 256), dim3(256), 0, stream>>>(src, dst, cur, cidx, e);

    pack_w6<<<dim3(384), dim3(256), 0, stream>>>(dW1, dW2, Ws0, Wn0, Ws1, Wn1, Wpk, mode);

    // ---- layer 0: h1 = relu(x@Ws0 + mean@Wn0 + b0) ----
    agg_gather<<<dim3((n * 64 + 255) / 256), dim3(256), 0, stream>>>(
        x, rowptr, cidx, aggb, mode, 1, n);
    sage_mfma<true><<<dim3((n + 63) / 64), dim3(256), 0, stream>>>(
        x, aggb, Ws0p, Wn0p, b0, h1, mode, 1, n);

    // ---- layer 1: h2 = h1@Ws1 + mean(h1)@Wn1 + b1  (h2 aliases aggb) ----
    agg_gather<<<dim3((n * 64 + 255) / 256), dim3(256), 0, stream>>>(
        h1, rowptr, cidx, aggb, mode, 0, n);
    sage_mfma<false><<<dim3((n + 63) / 64), dim3(256), 0, stream>>>(
        h1, aggb, Ws1p, Wn1p, b1, aggb /*h2 in-place*/, mode, 0, n);

    // ---- fused pos+neg decoder on h2 (bf16) ----
    edge_decode_mfma<<<dim3(PB + NDB), dim3(256), 0, stream>>>(
        aggb, pos_src, pos_dst, ep, PB, neg_src, neg_dst, en,
        W1p, db1, W2p, db2, dW3, db3, d_out, mode);
}

// Round 13
// 346.724 us; speedup vs baseline: 1.1497x; 1.0524x over previous
//
#include <hip/hip_runtime.h>
#include <hip/hip_bf16.h>

#define HD 128

typedef unsigned int u32;
typedef unsigned short u16;
typedef __attribute__((ext_vector_type(8))) short short8;   // 8 bf16 (4 VGPRs)
typedef __attribute__((ext_vector_type(4))) float f32x4;    // MFMA C/D

__device__ __forceinline__ float bf2f(u16 u) {
    return __uint_as_float(((u32)u) << 16);
}
__device__ __forceinline__ u16 f2bf(float f) {
    u32 u = __float_as_uint(f);
    u32 r = (u + 0x7fffu + ((u >> 16) & 1u)) >> 16;   // RNE
    return (u16)r;
}
// packed RNE f32x2 -> bf16x2; lo -> low 16 bits
__device__ __forceinline__ u32 pk2bf(float lo, float hi) {
    __hip_bfloat162 h = __float22bfloat162_rn(make_float2(lo, hi));
    union { __hip_bfloat162 h; u32 u; } cv; cv.h = h;
    return cv.u;
}
// packed bf16x2 multiply (RNE)
__device__ __forceinline__ u32 hmul2(u32 a, u32 b) {
    union { u32 u; __hip_bfloat162 h; } x, y, r;
    x.u = a; y.u = b;
    r.h = __hmul2(x.h, y.h);
    return r.u;
}
__device__ __forceinline__ float ldf(const void* p, size_t i, bool f32m) {
    return f32m ? ((const float*)p)[i] : bf2f(((const u16*)p)[i]);
}
// XOR-swizzled halfword index into a 64x128 bf16 LDS tile (16B-block swizzle).
__device__ __forceinline__ int swz(int row, int col) {
    return row * 128 + ((((col >> 3) ^ (row & 7)) << 3) | (col & 7));
}
__device__ __forceinline__ void acc8_bf16(uint4 v, float* a) {
    a[0] += __uint_as_float(v.x << 16); a[1] += __uint_as_float(v.x & 0xffff0000u);
    a[2] += __uint_as_float(v.y << 16); a[3] += __uint_as_float(v.y & 0xffff0000u);
    a[4] += __uint_as_float(v.z << 16); a[5] += __uint_as_float(v.z & 0xffff0000u);
    a[6] += __uint_as_float(v.w << 16); a[7] += __uint_as_float(v.w & 0xffff0000u);
}

// ---- dtype detector (parallel) ----
__global__ void detect_mode(const u32* __restrict__ x, int* __restrict__ mode) {
    __shared__ int cnt_s;
    if (threadIdx.x == 0) cnt_s = 0;
    __syncthreads();
    u32 e = (x[threadIdx.x] >> 23) & 0xFFu;
    if (e >= 90u && e < 170u) atomicAdd(&cnt_s, 1);
    __syncthreads();
    if (threadIdx.x == 0) mode[0] = (cnt_s >= 128) ? 1 : 0;
}

// ---- pack six 128x128 weight matrices into MFMA fragment order (bf16) ----
__global__ void pack_w6(const void* __restrict__ W0, const void* __restrict__ W1,
                        const void* __restrict__ W2, const void* __restrict__ W3,
                        const void* __restrict__ W4, const void* __restrict__ W5,
                        u16* __restrict__ out, const int* __restrict__ gmode) {
    const bool f32m = gmode[0] != 0;
    int gid = blockIdx.x * 256 + threadIdx.x;
    if (gid >= 6 * 16384) return;
    int sel = gid >> 14, idx = gid & 16383;
    const void* W = sel == 0 ? W0 : sel == 1 ? W1 : sel == 2 ? W2 :
                    sel == 3 ? W3 : sel == 4 ? W4 : W5;
    int j = idx & 7, lane = (idx >> 3) & 63, ks = (idx >> 9) & 3, nt = idx >> 11;
    int k = ks * 32 + (lane >> 4) * 8 + j;
    int n = nt * 16 + (lane & 15);
    out[gid] = f2bf(ldf(W, (size_t)k * HD + n, f32m));
}

// ================= CSR build ===========
__global__ void cnt_count(const int* __restrict__ dst, int* __restrict__ cnt, int e) {
    int i = blockIdx.x * 256 + threadIdx.x;
    if (i < e) atomicAdd(&cnt[dst[i]], 1);
}

__global__ void scan_blocks(const int* __restrict__ cnt, int* __restrict__ rowptr,
                            int* __restrict__ bsum, int n) {
    __shared__ int s[256];
    int t = threadIdx.x, gid = blockIdx.x * 256 + t;
    int v = (gid < n) ? cnt[gid] : 0;
    s[t] = v; __syncthreads();
    #pragma unroll
    for (int off = 1; off < 256; off <<= 1) {
        int x = (t >= off) ? s[t - off] : 0;
        __syncthreads();
        s[t] += x;
        __syncthreads();
    }
    if (gid < n) rowptr[gid] = s[t] - v;
    if (t == 255) bsum[blockIdx.x] = s[255];
}

__global__ void scan_bsum(int* __restrict__ bsum, int nb) {
    __shared__ int s[1024];
    __shared__ int carry;
    int t = threadIdx.x;
    if (t == 0) carry = 0;
    __syncthreads();
    for (int base = 0; base < nb; base += 1024) {
        int i = base + t;
        int v = (i < nb) ? bsum[i] : 0;
        s[t] = v; __syncthreads();
        #pragma unroll
        for (int off = 1; off < 1024; off <<= 1) {
            int x = (t >= off) ? s[t - off] : 0;
            __syncthreads();
            s[t] += x;
            __syncthreads();
        }
        if (i < nb) bsum[i] = carry + s[t] - v;
        __syncthreads();
        if (t == 0) carry += s[1023];
        __syncthreads();
    }
}

// rowptr finalize + cursor init (cur = rowptr)
__global__ void scan_add(int* __restrict__ rowptr, const int* __restrict__ bsum,
                         int* __restrict__ cur, int n, int e) {
    int gid = blockIdx.x * 256 + threadIdx.x;
    if (gid < n) {
        int v = rowptr[gid] + bsum[blockIdx.x];
        rowptr[gid] = v;
        cur[gid] = v;
    } else if (gid == n) {
        rowptr[n] = e;
    }
}

__global__ void csr_fill(const int* __restrict__ src, const int* __restrict__ dst,
                         int* __restrict__ cur, int* __restrict__ cidx, int e) {
    int i = blockIdx.x * 256 + threadIdx.x;
    if (i >= e) return;
    int p = atomicAdd(&cur[dst[i]], 1);
    cidx[p] = src[i];
}

// ---- fused MFMA SAGE layer: in-kernel CSR gather, one 16 KB tile ----
// pass A: stage X tile, MFMA with Ws. pass B: 16-lane groups gather neighbor
// rows (16 B/lane = full bf16 row) directly into the tile, MFMA with Wn.
template <bool RELU>
__global__ __launch_bounds__(256) void sage_mfma(
    const void* __restrict__ X, const int* __restrict__ rowptr,
    const int* __restrict__ cidx,
    const u16* __restrict__ Wsp, const u16* __restrict__ Wnp,
    const void* __restrict__ bias, u16* __restrict__ hout,
    const int* __restrict__ gmode, int use_mode, int n) {
    __shared__ u16 z[64 * 128];   // swizzled tile, 16 KB
    const bool f32m = gmode[0] != 0;
    const bool inf32 = use_mode && f32m;
    const int t = threadIdx.x;
    const int n0 = blockIdx.x * 64;
    const int lane = t & 63;
    const int w = t >> 6;
    const int cl = lane & 15, quad = lane >> 4;
    const int l16 = lane & 15, g = lane >> 4;

    // ---- pass A: stage X tile ----
    #pragma unroll
    for (int i = 0; i < 4; i++) {
        int idx = t + i * 256;
        int e = idx >> 4, sg = (idx & 15) * 8;
        int node = n0 + e;
        uint4 p = make_uint4(0, 0, 0, 0);
        if (node < n) {
            if (inf32) {
                const float* xp = (const float*)X + (size_t)node * HD + sg;
                float4 v0 = *(const float4*)xp, v1 = *(const float4*)(xp + 4);
                p.x = pk2bf(v0.x, v0.y); p.y = pk2bf(v0.z, v0.w);
                p.z = pk2bf(v1.x, v1.y); p.w = pk2bf(v1.z, v1.w);
            } else {
                p = *(const uint4*)((const u16*)X + (size_t)node * HD + sg);
            }
        }
        *(uint4*)&z[swz(e, sg)] = p;
    }
    __syncthreads();

    f32x4 acc[2][4];
    #pragma unroll
    for (int ft = 0; ft < 2; ft++) {
        int f0 = w * 32 + ft * 16 + quad * 4;
        f32x4 bv;
        bv[0] = ldf(bias, f0 + 0, f32m);
        bv[1] = ldf(bias, f0 + 1, f32m);
        bv[2] = ldf(bias, f0 + 2, f32m);
        bv[3] = ldf(bias, f0 + 3, f32m);
        #pragma unroll
        for (int et = 0; et < 4; et++) acc[ft][et] = bv;
    }
    #pragma unroll
    for (int ks = 0; ks < 4; ks++) {
        short8 a[2], b[4];
        #pragma unroll
        for (int ft = 0; ft < 2; ft++)
            a[ft] = ((const short8*)Wsp)[((w * 2 + ft) * 4 + ks) * 64 + lane];
        #pragma unroll
        for (int et = 0; et < 4; et++)
            b[et] = *(const short8*)&z[swz(et * 16 + cl, ks * 32 + quad * 8)];
        #pragma unroll
        for (int ft = 0; ft < 2; ft++)
            #pragma unroll
            for (int et = 0; et < 4; et++)
                acc[ft][et] = __builtin_amdgcn_mfma_f32_16x16x32_bf16(
                    a[ft], b[et], acc[ft][et], 0, 0, 0);
    }
    __syncthreads();   // all reads of X tile done

    // ---- pass B: fused gather of neighbor means into same tile ----
    // wave w owns rows [w*16, w*16+16); 16-lane group g handles rows w*16+r*4+g.
    #pragma unroll 1
    for (int r = 0; r < 4; r++) {
        int e = w * 16 + r * 4 + g;
        int node = n0 + e;
        float a[8] = {0.f, 0.f, 0.f, 0.f, 0.f, 0.f, 0.f, 0.f};
        int deg = 0;
        if (node < n) {
            int s0 = rowptr[node], s1 = rowptr[node + 1];
            deg = s1 - s0;
            int i = s0;
            if (inf32) {
                for (; i + 1 < s1; i += 2) {
                    const float* pA = (const float*)X + (size_t)cidx[i] * HD + l16 * 8;
                    const float* pB = (const float*)X + (size_t)cidx[i + 1] * HD + l16 * 8;
                    float4 a0 = *(const float4*)pA, a1 = *(const float4*)(pA + 4);
                    float4 b0 = *(const float4*)pB, b1 = *(const float4*)(pB + 4);
                    a[0] += a0.x + b0.x; a[1] += a0.y + b0.y;
                    a[2] += a0.z + b0.z; a[3] += a0.w + b0.w;
                    a[4] += a1.x + b1.x; a[5] += a1.y + b1.y;
                    a[6] += a1.z + b1.z; a[7] += a1.w + b1.w;
                }
                if (i < s1) {
                    const float* pA = (const float*)X + (size_t)cidx[i] * HD + l16 * 8;
                    float4 a0 = *(const float4*)pA, a1 = *(const float4*)(pA + 4);
                    a[0] += a0.x; a[1] += a0.y; a[2] += a0.z; a[3] += a0.w;
                    a[4] += a1.x; a[5] += a1.y; a[6] += a1.z; a[7] += a1.w;
                }
            } else {
                for (; i + 1 < s1; i += 2) {
                    uint4 vA = *(const uint4*)((const u16*)X + (size_t)cidx[i] * HD + l16 * 8);
                    uint4 vB = *(const uint4*)((const u16*)X + (size_t)cidx[i + 1] * HD + l16 * 8);
                    acc8_bf16(vA, a);
                    acc8_bf16(vB, a);
                }
                if (i < s1) {
                    uint4 vA = *(const uint4*)((const u16*)X + (size_t)cidx[i] * HD + l16 * 8);
                    acc8_bf16(vA, a);
                }
            }
        }
        float iv = 1.f / fmaxf((float)deg, 1.f);
        uint4 o;
        o.x = pk2bf(a[0] * iv, a[1] * iv);
        o.y = pk2bf(a[2] * iv, a[3] * iv);
        o.z = pk2bf(a[4] * iv, a[5] * iv);
        o.w = pk2bf(a[6] * iv, a[7] * iv);
        *(uint4*)&z[swz(e, l16 * 8)] = o;
    }
    __syncthreads();

    #pragma unroll
    for (int ks = 0; ks < 4; ks++) {
        short8 a[2], b[4];
        #pragma unroll
        for (int ft = 0; ft < 2; ft++)
            a[ft] = ((const short8*)Wnp)[((w * 2 + ft) * 4 + ks) * 64 + lane];
        #pragma unroll
        for (int et = 0; et < 4; et++)
            b[et] = *(const short8*)&z[swz(et * 16 + cl, ks * 32 + quad * 8)];
        #pragma unroll
        for (int ft = 0; ft < 2; ft++)
            #pragma unroll
            for (int et = 0; et < 4; et++)
                acc[ft][et] = __builtin_amdgcn_mfma_f32_16x16x32_bf16(
                    a[ft], b[et], acc[ft][et], 0, 0, 0);
    }
    __syncthreads();   // all reads done before epilogue aliasing

    // ---- epilogue: packed b64 swizzled LDS writes, coalesced global copy ----
    #pragma unroll
    for (int ft = 0; ft < 2; ft++) {
        int f0 = w * 32 + ft * 16 + quad * 4;
        #pragma unroll
        for (int et = 0; et < 4; et++) {
            f32x4 v = acc[ft][et];
            float v0 = RELU ? fmaxf(v[0], 0.f) : v[0];
            float v1 = RELU ? fmaxf(v[1], 0.f) : v[1];
            float v2 = RELU ? fmaxf(v[2], 0.f) : v[2];
            float v3 = RELU ? fmaxf(v[3], 0.f) : v[3];
            *(uint2*)&z[swz(et * 16 + cl, f0)] =
                make_uint2(pk2bf(v0, v1), pk2bf(v2, v3));
        }
    }
    __syncthreads();
    #pragma unroll
    for (int i = 0; i < 4; i++) {
        int idx = t + i * 256;
        int e = idx >> 4, sg = (idx & 15) * 8;
        int node = n0 + e;
        if (node < n)
            *(uint4*)&hout[(size_t)node * HD + sg] = *(const uint4*)&z[swz(e, sg)];
    }
}

// ---- MFMA edge decoder, pos+neg fused; ONE tile (17.4 KB, 8 blocks/CU) ----
__global__ __launch_bounds__(256) void edge_decode_mfma(
    const u16* __restrict__ h,
    const int* __restrict__ psrc, const int* __restrict__ pdst, int ep, int PB,
    const int* __restrict__ nsrc, const int* __restrict__ ndst, int en,
    const u16* __restrict__ W1p, const void* __restrict__ b1,
    const u16* __restrict__ W2p, const void* __restrict__ b2,
    const void* __restrict__ W3, const void* __restrict__ b3,
    void* __restrict__ out, const int* __restrict__ gmode) {
    __shared__ u16 zA[64 * 128];
    __shared__ float psum[256];
    const bool f32m = gmode[0] != 0;
    const int t = threadIdx.x;
    const int b = blockIdx.x;
    const int* esrc; const int* edst; int e0, obase, ne;
    if (b < PB) { esrc = psrc; edst = pdst; e0 = b * 64;        obase = 0;  ne = ep; }
    else        { esrc = nsrc; edst = ndst; e0 = (b - PB) * 64; obase = ep; ne = en; }
    const int lane = t & 63;
    const int w = t >> 6;
    const int cl = lane & 15, quad = lane >> 4;

    // ---- stage z0 = bf16(h[s]*h[d]): 16 B/lane, packed bf16 mul ----
    #pragma unroll
    for (int i = 0; i < 4; i++) {
        int idx = t + i * 256;
        int e = idx >> 4, sg = (idx & 15) * 8;
        int eg = e0 + e;
        uint4 z = make_uint4(0, 0, 0, 0);
        if (eg < ne) {
            int s = esrc[eg], d = edst[eg];
            uint4 a  = *(const uint4*)(h + (size_t)s * HD + sg);
            uint4 bv = *(const uint4*)(h + (size_t)d * HD + sg);
            z.x = hmul2(a.x, bv.x); z.y = hmul2(a.y, bv.y);
            z.z = hmul2(a.z, bv.z); z.w = hmul2(a.w, bv.w);
        }
        *(uint4*)&zA[swz(e, sg)] = z;
    }
    __syncthreads();

    // ---- gemm1: acc in registers ----
    f32x4 acc[2][4];
    #pragma unroll
    for (int ft = 0; ft < 2; ft++) {
        int f0 = w * 32 + ft * 16 + quad * 4;
        f32x4 bv;
        bv[0] = ldf(b1, f0 + 0, f32m);
        bv[1] = ldf(b1, f0 + 1, f32m);
        bv[2] = ldf(b1, f0 + 2, f32m);
        bv[3] = ldf(b1, f0 + 3, f32m);
        #pragma unroll
        for (int et = 0; et < 4; et++) acc[ft][et] = bv;
    }
    #pragma unroll
    for (int ks = 0; ks < 4; ks++) {
        short8 a[2], bb[4];
        #pragma unroll
        for (int ft = 0; ft < 2; ft++)
            a[ft] = ((const short8*)W1p)[((w * 2 + ft) * 4 + ks) * 64 + lane];
        #pragma unroll
        for (int et = 0; et < 4; et++)
            bb[et] = *(const short8*)&zA[swz(et * 16 + cl, ks * 32 + quad * 8)];
        #pragma unroll
        for (int ft = 0; ft < 2; ft++)
            #pragma unroll
            for (int et = 0; et < 4; et++)
                acc[ft][et] = __builtin_amdgcn_mfma_f32_16x16x32_bf16(
                    a[ft], bb[et], acc[ft][et], 0, 0, 0);
    }
    __syncthreads();   // all reads of z0 done

    // ---- write relu(z1) back into the SAME tile ----
    #pragma unroll
    for (int ft = 0; ft < 2; ft++) {
        int f0 = w * 32 + ft * 16 + quad * 4;
        #pragma unroll
        for (int et = 0; et < 4; et++) {
            f32x4 v = acc[ft][et];
            *(uint2*)&zA[swz(et * 16 + cl, f0)] = make_uint2(
                pk2bf(fmaxf(v[0], 0.f), fmaxf(v[1], 0.f)),
                pk2bf(fmaxf(v[2], 0.f), fmaxf(v[3], 0.f)));
        }
    }
    __syncthreads();

    // ---- gemm2 in registers + W3 dot ----
    #pragma unroll
    for (int ft = 0; ft < 2; ft++) {
        int f0 = w * 32 + ft * 16 + quad * 4;
        f32x4 bv;
        bv[0] = ldf(b2, f0 + 0, f32m);
        bv[1] = ldf(b2, f0 + 1, f32m);
        bv[2] = ldf(b2, f0 + 2, f32m);
        bv[3] = ldf(b2, f0 + 3, f32m);
        #pragma unroll
        for (int et = 0; et < 4; et++) acc[ft][et] = bv;
    }
    #pragma unroll
    for (int ks = 0; ks < 4; ks++) {
        short8 a[2], bb[4];
        #pragma unroll
        for (int ft = 0; ft < 2; ft++)
            a[ft] = ((const short8*)W2p)[((w * 2 + ft) * 4 + ks) * 64 + lane];
        #pragma unroll
        for (int et = 0; et < 4; et++)
            bb[et] = *(const short8*)&zA[swz(et * 16 + cl, ks * 32 + quad * 8)];
        #pragma unroll
        for (int ft = 0; ft < 2; ft++)
            #pragma unroll
            for (int et = 0; et < 4; et++)
                acc[ft][et] = __builtin_amdgcn_mfma_f32_16x16x32_bf16(
                    a[ft], bb[et], acc[ft][et], 0, 0, 0);
    }
    // per-lane partial dot of relu(z2) with W3 over this lane's 8 feats
    float p[4] = {0.f, 0.f, 0.f, 0.f};
    #pragma unroll
    for (int ft = 0; ft < 2; ft++) {
        int f0 = w * 32 + ft * 16 + quad * 4;
        float w3v0 = ldf(W3, f0 + 0, f32m);
        float w3v1 = ldf(W3, f0 + 1, f32m);
        float w3v2 = ldf(W3, f0 + 2, f32m);
        float w3v3 = ldf(W3, f0 + 3, f32m);
        #pragma unroll
        for (int et = 0; et < 4; et++) {
            f32x4 v = acc[ft][et];
            p[et] = fmaf(fmaxf(v[0], 0.f), w3v0, p[et]);
            p[et] = fmaf(fmaxf(v[1], 0.f), w3v1, p[et]);
            p[et] = fmaf(fmaxf(v[2], 0.f), w3v2, p[et]);
            p[et] = fmaf(fmaxf(v[3], 0.f), w3v3, p[et]);
        }
    }
    #pragma unroll
    for (int et = 0; et < 4; et++) {
        p[et] += __shfl_xor(p[et], 16);
        p[et] += __shfl_xor(p[et], 32);
    }
    if (lane < 16) {
        #pragma unroll
        for (int et = 0; et < 4; et++)
            psum[w * 64 + et * 16 + lane] = p[et];
    }
    __syncthreads();
    if (t < 64) {
        int eg = e0 + t;
        if (eg < ne) {
            float sum = ldf(b3, 0, f32m) + (psum[t] + psum[64 + t])
                      + (psum[128 + t] + psum[192 + t]);
            if (f32m) ((float*)out)[obase + eg] = sum;
            else      ((u16*)out)[obase + eg]   = f2bf(sum);
        }
    }
}

extern "C" void kernel_launch(void* const* d_in, const int* in_sizes, int n_in,
                              void* d_out, int out_size, void* d_ws, size_t ws_size,
                              hipStream_t stream) {
    const void* x      = d_in[0];
    const int* src     = (const int*)d_in[1];
    const int* dst     = (const int*)d_in[2];
    const int* pos_src = (const int*)d_in[3];
    const int* pos_dst = (const int*)d_in[4];
    const int* neg_src = (const int*)d_in[5];
    const int* neg_dst = (const int*)d_in[6];
    const void* Ws0 = d_in[7];
    const void* Wn0 = d_in[8];
    const void* b0  = d_in[9];
    const void* Ws1 = d_in[10];
    const void* Wn1 = d_in[11];
    const void* b1  = d_in[12];
    const void* dW1 = d_in[13];
    const void* db1 = d_in[14];
    const void* dW2 = d_in[15];
    const void* db2 = d_in[16];
    const void* dW3 = d_in[17];
    const void* db3 = d_in[18];

    const int n  = in_sizes[0] / HD;
    const int e  = in_sizes[1];
    const int ep = in_sizes[3];
    const int en = in_sizes[5];
    const int NB = (n + 255) / 256;
    const int PB = (ep + 63) / 64, NDB = (en + 63) / 64;

    // ws: h2[n*HD] u16 | h1[n*HD] u16 | mode | rowptr | cur | cidx | bsum | packed W x6
    char* base = (char*)d_ws;
    u16* h2 = (u16*)d_ws;
    u16* h1 = h2 + (size_t)n * HD;
    size_t off = (size_t)n * HD * 4;
    int* mode = (int*)(base + off);      off += 16;
    int* rowptr = (int*)(base + off);    off += (size_t)(n + 1) * 4; off = (off + 15) & ~(size_t)15;
    int* cur = (int*)(base + off);       off += (size_t)n * 4;       off = (off + 15) & ~(size_t)15;
    int* cidx = (int*)(base + off);      off += (size_t)e * 4;       off = (off + 15) & ~(size_t)15;
    int* bsum = (int*)(base + off);      off += (size_t)NB * 4;      off = (off + 15) & ~(size_t)15;
    u16* Wpk  = (u16*)(base + off);      // order: dW1, dW2, Ws0, Wn0, Ws1, Wn1
    u16* W1p  = Wpk;
    u16* W2p  = Wpk + 16384;
    u16* Ws0p = Wpk + 2 * 16384;
    u16* Wn0p = Wpk + 3 * 16384;
    u16* Ws1p = Wpk + 4 * 16384;
    u16* Wn1p = Wpk + 5 * 16384;

    detect_mode<<<dim3(1), dim3(256), 0, stream>>>((const u32*)x, mode);

    // ---- CSR build (once) ----
    hipMemsetAsync(cur, 0, (size_t)n * 4, stream);   // cur doubles as cnt
    cnt_count<<<dim3((e + 255) / 256), dim3(256), 0, stream>>>(dst, cur, e);
    scan_blocks<<<dim3(NB), dim3(256), 0, stream>>>(cur, rowptr, bsum, n);
    scan_bsum<<<dim3(1), dim3(1024), 0, stream>>>(bsum, NB);
    scan_add<<<dim3((n + 256) / 256), dim3(256), 0, stream>>>(rowptr, bsum, cur, n, e);
    csr_fill<<<dim3((e + 255) / 256), dim3(256), 0, stream>>>(src, dst, cur, cidx, e);

    pack_w6<<<dim3(384), dim3(256), 0, stream>>>(dW1, dW2, Ws0, Wn0, Ws1, Wn1, Wpk, mode);

    // ---- layer 0 (fused gather): h1 = relu(x@Ws0 + mean(x)@Wn0 + b0) ----
    sage_mfma<true><<<dim3((n + 63) / 64), dim3(256), 0, stream>>>(
        x, rowptr, cidx, Ws0p, Wn0p, b0, h1, mode, 1, n);

    // ---- layer 1 (fused gather): h2 = h1@Ws1 + mean(h1)@Wn1 + b1 ----
    sage_mfma<false><<<dim3((n + 63) / 64), dim3(256), 0, stream>>>(
        h1, rowptr, cidx, Ws1p, Wn1p, b1, h2, mode, 0, n);

    // ---- fused pos+neg decoder on h2 (bf16) ----
    edge_decode_mfma<<<dim3(PB + NDB), dim3(256), 0, stream>>>(
        h2, pos_src, pos_dst, ep, PB, neg_src, neg_dst, en,
        W1p, db1, W2p, db2, dW3, db3, d_out, mode);
}